// Round 12
// baseline (248.081 us; speedup 1.0000x reference)
//
#include <hip/hip_runtime.h>

typedef unsigned int uint;
typedef unsigned short ushort;

#define IN_C 128
#define HID  32
#define CDIM 224
#define OUT_C 16

// ---- bf16 helpers (fp32 accumulate everywhere; RNE on store) --------------
__device__ __forceinline__ float bf_lo(uint u) { return __uint_as_float(u << 16); }
__device__ __forceinline__ float bf_hi(uint u) { return __uint_as_float(u & 0xffff0000u); }
__device__ __forceinline__ uint  f2bf(float f) {
    uint u = __float_as_uint(f);
    return (u + 0x7fffu + ((u >> 16) & 1u)) >> 16;   // RNE; inputs are finite
}
__device__ __forceinline__ float inv_sqrt_deg(int d) {
    return d > 0 ? 1.f / sqrtf((float)d) : 0.f;      // matches reference norm()
}

// ---------------------------------------------------------------------------
// K1: fused prep (R7/R10 structure — fast under the harness DMA flood):
//   blocks [0,nbE)        : r0 = relu(x @ w_embed) -> bf16
//   blocks [nbE,nbE+nbI)  : both CSR indptrs by binary search
//   blocks [nbE+nbI,+nbT) : warm-touch A2 col+val into LLC
// ---------------------------------------------------------------------------
__global__ void prep_kernel(const float* __restrict__ x,
                            const float* __restrict__ w,
                            ushort* __restrict__ r0,
                            const int* __restrict__ a1r, int E1, int* __restrict__ ip1,
                            const int* __restrict__ a2r, int E2, int* __restrict__ ip2,
                            const int* __restrict__ a2c, const float* __restrict__ a2v,
                            float* __restrict__ dummy,
                            int n, int nbE, int nbI, int nbT) {
    __shared__ float wl[IN_C * HID];
    const int tid = threadIdx.x;
    if (blockIdx.x < nbE) {
        for (int i = tid; i < IN_C * HID; i += blockDim.x) wl[i] = w[i];
        __syncthreads();
        const int row = blockIdx.x * 16 + tid / 16;
        const int h0  = (tid % 16) * 2;
        if (row >= n) return;
        const float4* xr = (const float4*)(x + (size_t)row * IN_C);
        float a0 = 0.f, a1 = 0.f;
#pragma unroll
        for (int k4 = 0; k4 < IN_C / 4; ++k4) {
            float4 xv = xr[k4];
            a0 += xv.x * wl[(4*k4+0)*HID + h0];  a1 += xv.x * wl[(4*k4+0)*HID + h0+1];
            a0 += xv.y * wl[(4*k4+1)*HID + h0];  a1 += xv.y * wl[(4*k4+1)*HID + h0+1];
            a0 += xv.z * wl[(4*k4+2)*HID + h0];  a1 += xv.z * wl[(4*k4+2)*HID + h0+1];
            a0 += xv.w * wl[(4*k4+3)*HID + h0];  a1 += xv.w * wl[(4*k4+3)*HID + h0+1];
        }
        uint p = f2bf(fmaxf(a0, 0.f)) | (f2bf(fmaxf(a1, 0.f)) << 16);
        ((uint*)r0)[(size_t)row * 16 + (tid % 16)] = p;
    } else if (blockIdx.x < nbE + nbI) {
        const int i = (blockIdx.x - nbE) * 256 + tid;
        if (i > n) return;
        int lo = 0, hi = E1;
        while (lo < hi) { int m = (lo + hi) >> 1; if (a1r[m] < i) lo = m + 1; else hi = m; }
        ip1[i] = lo;
        lo = 0; hi = E2;
        while (lo < hi) { int m = (lo + hi) >> 1; if (a2r[m] < i) lo = m + 1; else hi = m; }
        ip2[i] = lo;
    } else {
        const int t = (blockIdx.x - nbE - nbI) * 256 + tid;
        const int stride = nbT * 256;
        const int total4 = E2 / 4;
        const float4* c4 = (const float4*)a2c;
        const float4* v4 = (const float4*)a2v;
        float s = 0.f;
        for (int i = t; i < total4; i += stride) {
            float4 u = c4[i], v = v4[i];
            s += u.x + u.y + u.z + u.w + v.x + v.y + v.z + v.w;
        }
        if (s == 123.456f) dummy[0] = s;   // defeats DCE; never taken in practice
    }
}

// ---------------------------------------------------------------------------
// K2: level-1 SpMM + ReLU (with val), bf16 / fp32 acc. R10 structure.
// ROWS=2 rows/wave; L=4 feature-lanes x W=8 ways, 4-edge int4 batches.
// Epilogue also emits y1/y2 = dis1/dis2-scaled outputs for level 2.
// Blocks [0,nb2) = A2 (out col off C); rest = A1 (off 0).
// ---------------------------------------------------------------------------
template <int C, int ROWS>
__global__ __launch_bounds__(256) void spmm_l1(
        const int* __restrict__ ip1, const int* __restrict__ col1,
        const float* __restrict__ val1,
        const int* __restrict__ ip2, const int* __restrict__ col2,
        const float* __restrict__ val2,
        const ushort* __restrict__ xin,
        ushort* __restrict__ rout,
        ushort* __restrict__ yout1, ushort* __restrict__ yout2,
        int n, int nb2) {
    constexpr int L    = C / 8;
    constexpr int SUBL = 64 / ROWS;
    constexpr int W    = SUBL / L;
    const int lane = threadIdx.x & 63;
    const int wave = threadIdx.x >> 6;
    const int sub  = lane / SUBL;
    const int li   = lane % SUBL;
    const int fl   = li % L;
    const int way  = li / L;

    int bid = blockIdx.x;
    const int* ip; const int* col; const float* val; int off;
    if (bid < nb2) {             ip = ip2; col = col2; val = val2; off = C; }
    else           { bid -= nb2; ip = ip1; col = col1; val = val1; off = 0; }

    const int row = (bid * 4 + wave) * ROWS + sub;
    if (row >= n) return;

    const ushort* xbase = xin + fl * 8;
    float acc[8];
#pragma unroll
    for (int j = 0; j < 8; ++j) acc[j] = 0.f;

    auto gat = [&](int c) -> uint4 { return *(const uint4*)(xbase + (size_t)c * C); };
    auto fmadd = [&](const uint4& u, float v) {
        acc[0] += v * bf_lo(u.x); acc[1] += v * bf_hi(u.x);
        acc[2] += v * bf_lo(u.y); acc[3] += v * bf_hi(u.y);
        acc[4] += v * bf_lo(u.z); acc[5] += v * bf_hi(u.z);
        acc[6] += v * bf_lo(u.w); acc[7] += v * bf_hi(u.w);
    };

    const int s = ip[row];
    const int e = ip[row + 1];
    int sv = (s + 3) & ~3; if (sv > e) sv = e;
    const int nv = (e - sv) / (4 * W);

    for (int idx = s + way; idx < sv; idx += W) fmadd(gat(col[idx]), val[idx]);
    const int*   cb = col + sv;
    const float* vb = val + sv;
    for (int i = 0; i < nv; ++i) {
        const int base = (i * W + way) * 4;
        const int4   cc = *(const int4*)  (cb + base);
        const float4 vv = *(const float4*)(vb + base);
        const uint4 g0 = gat(cc.x), g1 = gat(cc.y), g2 = gat(cc.z), g3 = gat(cc.w);
        fmadd(g0, vv.x); fmadd(g1, vv.y); fmadd(g2, vv.z); fmadd(g3, vv.w);
    }
    for (int idx = sv + nv * 4 * W + way; idx < e; idx += W)
        fmadd(gat(col[idx]), val[idx]);

#pragma unroll
    for (int m = L; m < SUBL; m <<= 1)
#pragma unroll
        for (int j = 0; j < 8; ++j) acc[j] += __shfl_xor(acc[j], m, 64);

    if (way == 0) {
        float r[8];
#pragma unroll
        for (int j = 0; j < 8; ++j) r[j] = fmaxf(acc[j], 0.f);

        const size_t oidx = (size_t)row * (2 * C) + off + fl * 8;
        uint4 p;
        p.x = f2bf(r[0]) | (f2bf(r[1]) << 16);
        p.y = f2bf(r[2]) | (f2bf(r[3]) << 16);
        p.z = f2bf(r[4]) | (f2bf(r[5]) << 16);
        p.w = f2bf(r[6]) | (f2bf(r[7]) << 16);
        *(uint4*)(rout + oidx) = p;

        const float s1 = inv_sqrt_deg(ip1[row + 1] - ip1[row]);
        const float s2 = inv_sqrt_deg(ip2[row + 1] - ip2[row]);
        uint4 q1, q2;
        q1.x = f2bf(s1*r[0]) | (f2bf(s1*r[1]) << 16);
        q1.y = f2bf(s1*r[2]) | (f2bf(s1*r[3]) << 16);
        q1.z = f2bf(s1*r[4]) | (f2bf(s1*r[5]) << 16);
        q1.w = f2bf(s1*r[6]) | (f2bf(s1*r[7]) << 16);
        q2.x = f2bf(s2*r[0]) | (f2bf(s2*r[1]) << 16);
        q2.y = f2bf(s2*r[2]) | (f2bf(s2*r[3]) << 16);
        q2.z = f2bf(s2*r[4]) | (f2bf(s2*r[5]) << 16);
        q2.w = f2bf(s2*r[6]) | (f2bf(s2*r[7]) << 16);
        *(uint4*)(yout1 + oidx) = q1;
        *(uint4*)(yout2 + oidx) = q2;
    }
}

// ---------------------------------------------------------------------------
// K3: FUSED level-2 SpMM + ReLU + classify. One wave per row.
// Gather phase (val-free, pre-scaled y feats): A2-half into acc2, A1-half
// into acc1; L=8 x W=8, 4-edge int4 batches. Cross-way xor-reduce gives ALL
// lanes the full row sums. Epilogue: row-side dis + relu -> r2 row in regs;
// classify dot [224x16] with w in LDS: lane (fl = lane&7, way = lane>>3)
// covers feature-chunk fl x outputs {2*way, 2*way+1}; r1 chunk fl and r0
// chunk (fl<4) loaded directly; 3-stage xor-reduce over fl; float2 store.
// r2 never touches memory; classify kernel eliminated.
// ---------------------------------------------------------------------------
__global__ __launch_bounds__(256) void spmm2_cls(
        const int* __restrict__ ip1, const int* __restrict__ col1,
        const int* __restrict__ ip2, const int* __restrict__ col2,
        const ushort* __restrict__ y1, const ushort* __restrict__ y2,
        const ushort* __restrict__ r0, const ushort* __restrict__ r1,
        const float* __restrict__ w, float* __restrict__ out, int n) {
    __shared__ float wl[CDIM * OUT_C];
    for (int i = threadIdx.x; i < CDIM * OUT_C; i += 256) wl[i] = w[i];
    // barrier deferred: wl is first used after the gather phase

    const int lane = threadIdx.x & 63;
    const int wave = threadIdx.x >> 6;
    const int row  = blockIdx.x * 4 + wave;
    const int fl   = lane & 7;     // feature chunk (8 bf16 = uint4)
    const int way  = lane >> 3;    // edge way / output-pair selector

    float acc1[8], acc2[8];
#pragma unroll
    for (int j = 0; j < 8; ++j) { acc1[j] = 0.f; acc2[j] = 0.f; }
    int deg1 = 0, deg2 = 0;

    if (row < n) {
        auto half = [&](const int* __restrict__ ip, const int* __restrict__ col,
                        const ushort* __restrict__ yb, float* acc, int& deg) {
            const int s = ip[row];
            const int e = ip[row + 1];
            deg = e - s;
            const ushort* xbase = yb + fl * 8;
            auto gat = [&](int c) -> uint4 {
                return *(const uint4*)(xbase + (size_t)c * 64);
            };
            auto aadd = [&](const uint4& u) {
                acc[0] += bf_lo(u.x); acc[1] += bf_hi(u.x);
                acc[2] += bf_lo(u.y); acc[3] += bf_hi(u.y);
                acc[4] += bf_lo(u.z); acc[5] += bf_hi(u.z);
                acc[6] += bf_lo(u.w); acc[7] += bf_hi(u.w);
            };
            int sv = (s + 3) & ~3; if (sv > e) sv = e;
            const int nv = (e - sv) / 32;          // 4 edges x 8 ways
            for (int idx = s + way; idx < sv; idx += 8) aadd(gat(col[idx]));
            const int* cb = col + sv;
            for (int i = 0; i < nv; ++i) {
                const int base = (i * 8 + way) * 4;
                const int4 cc = *(const int4*)(cb + base);
                const uint4 g0 = gat(cc.x), g1 = gat(cc.y),
                            g2 = gat(cc.z), g3 = gat(cc.w);
                aadd(g0); aadd(g1); aadd(g2); aadd(g3);
            }
            for (int idx = sv + nv * 32 + way; idx < e; idx += 8) aadd(gat(col[idx]));
        };
        half(ip2, col2, y2, acc2, deg2);   // heavy half first
        half(ip1, col1, y1, acc1, deg1);

        // cross-way reduce — butterfly leaves full sums in ALL lanes
#pragma unroll
        for (int m = 8; m < 64; m <<= 1)
#pragma unroll
            for (int j = 0; j < 8; ++j) {
                acc1[j] += __shfl_xor(acc1[j], m, 64);
                acc2[j] += __shfl_xor(acc2[j], m, 64);
            }
    }

    __syncthreads();                       // wl ready (all threads reach this)
    if (row >= n) return;

    const float s1 = inv_sqrt_deg(deg1);
    const float s2 = inv_sqrt_deg(deg2);
    float r2a[8], r2b[8];
#pragma unroll
    for (int j = 0; j < 8; ++j) {
        r2a[j] = fmaxf(s1 * acc1[j], 0.f);   // r2 cols [fl*8 .. ) of A1 half
        r2b[j] = fmaxf(s2 * acc2[j], 0.f);   // r2 cols [64+fl*8 .. ) of A2 half
    }

    const int o0 = way * 2;                // this lane's output pair
    float q0 = 0.f, q1 = 0.f;
    // r2 contributions (feats 96..223 of the concat)
#pragma unroll
    for (int j = 0; j < 8; ++j) {
        const int fA = (96 + fl * 8 + j) * OUT_C;
        const int fB = (160 + fl * 8 + j) * OUT_C;
        q0 += r2a[j] * wl[fA + o0];     q1 += r2a[j] * wl[fA + o0 + 1];
        q0 += r2b[j] * wl[fB + o0];     q1 += r2b[j] * wl[fB + o0 + 1];
    }
    // r1 chunk fl (feats 32..95)
    {
        const uint4 u = ((const uint4*)(r1 + (size_t)row * 64))[fl];
        float f[8];
        f[0]=bf_lo(u.x); f[1]=bf_hi(u.x); f[2]=bf_lo(u.y); f[3]=bf_hi(u.y);
        f[4]=bf_lo(u.z); f[5]=bf_hi(u.z); f[6]=bf_lo(u.w); f[7]=bf_hi(u.w);
#pragma unroll
        for (int j = 0; j < 8; ++j) {
            const int fi = (32 + fl * 8 + j) * OUT_C;
            q0 += f[j] * wl[fi + o0];   q1 += f[j] * wl[fi + o0 + 1];
        }
    }
    // r0 chunk (feats 0..31) — only fl<4
    if (fl < 4) {
        const uint4 u = ((const uint4*)(r0 + (size_t)row * 32))[fl];
        float f[8];
        f[0]=bf_lo(u.x); f[1]=bf_hi(u.x); f[2]=bf_lo(u.y); f[3]=bf_hi(u.y);
        f[4]=bf_lo(u.z); f[5]=bf_hi(u.z); f[6]=bf_lo(u.w); f[7]=bf_hi(u.w);
#pragma unroll
        for (int j = 0; j < 8; ++j) {
            const int fi = (fl * 8 + j) * OUT_C;
            q0 += f[j] * wl[fi + o0];   q1 += f[j] * wl[fi + o0 + 1];
        }
    }
    // reduce over fl (lanes differing in bits 0..2 share the same output pair)
#pragma unroll
    for (int m = 1; m < 8; m <<= 1) {
        q0 += __shfl_xor(q0, m, 64);
        q1 += __shfl_xor(q1, m, 64);
    }
    if (fl == 0) {
        float2 v; v.x = q0; v.y = q1;
        *(float2*)(out + (size_t)row * OUT_C + o0) = v;
    }
}

// ---------------------------------------------------------------------------
extern "C" void kernel_launch(void* const* d_in, const int* in_sizes, int n_in,
                              void* d_out, int out_size, void* d_ws, size_t ws_size,
                              hipStream_t stream) {
    const float* x   = (const float*)d_in[0];
    const float* we  = (const float*)d_in[1];
    const float* wc  = (const float*)d_in[2];
    const int*   a1r = (const int*)  d_in[3];
    const int*   a1c = (const int*)  d_in[4];
    const float* a1v = (const float*)d_in[5];
    const int*   a2r = (const int*)  d_in[6];
    const int*   a2c = (const int*)  d_in[7];
    const float* a2v = (const float*)d_in[8];
    float* out = (float*)d_out;

    const int E1 = in_sizes[3];
    const int E2 = in_sizes[6];
    const int n  = in_sizes[0] / IN_C;   // 20000

    // Workspace (bf16): r0[n*32] r1[n*64] y1_1[n*64] y2_1[n*64],
    // then ip1/ip2/dummy (int)
    ushort* r0   = (ushort*)d_ws;
    ushort* r1   = r0   + (size_t)n * 32;
    ushort* y1_1 = r1   + (size_t)n * 64;
    ushort* y2_1 = y1_1 + (size_t)n * 64;
    int*    ip1  = (int*)(y2_1 + (size_t)n * 64);
    int*    ip2  = ip1 + (n + 1);
    float*  dummy = (float*)(ip2 + (n + 1));

    // K1: fused prep (embed + indptrs + warm-touch)
    {
        const int nbE = (n + 15) / 16;
        const int nbI = (n + 1 + 255) / 256;
        const int nbT = 512;
        prep_kernel<<<nbE + nbI + nbT, 256, 0, stream>>>(
            x, we, r0, a1r, E1, ip1, a2r, E2, ip2, a2c, a2v, dummy,
            n, nbE, nbI, nbT);
    }
    // K2: level 1 (C=32, ROWS=2, with val) + scaled outputs for level 2
    {
        const int nb = (n + 7) / 8;
        spmm_l1<32, 2><<<2 * nb, 256, 0, stream>>>(
            ip1, a1c, a1v, ip2, a2c, a2v, r0, r1, y1_1, y2_1, n, nb);
    }
    // K3: fused level 2 + classify (one wave per row)
    {
        const int nb = (n + 3) / 4;
        spmm2_cls<<<nb, 256, 0, stream>>>(
            ip1, a1c, ip2, a2c, y1_1, y2_1, r0, r1, wc, out, n);
    }
}

// Round 13
// 230.192 us; speedup vs baseline: 1.0777x; 1.0777x over previous
//
#include <hip/hip_runtime.h>

typedef unsigned int uint;
typedef unsigned short ushort;

#define IN_C 128
#define HID  32
#define CDIM 224
#define OUT_C 16

// ---- bf16 helpers (fp32 accumulate everywhere; RNE on store) --------------
__device__ __forceinline__ float bf_lo(uint u) { return __uint_as_float(u << 16); }
__device__ __forceinline__ float bf_hi(uint u) { return __uint_as_float(u & 0xffff0000u); }
__device__ __forceinline__ uint  f2bf(float f) {
    uint u = __float_as_uint(f);
    return (u + 0x7fffu + ((u >> 16) & 1u)) >> 16;   // RNE; inputs are finite
}
__device__ __forceinline__ float inv_sqrt_deg(int d) {
    return d > 0 ? 1.f / sqrtf((float)d) : 0.f;      // matches reference norm()
}

// ---------------------------------------------------------------------------
// K1: fused prep (R7/R10 structure — fast under the harness DMA flood):
//   blocks [0,nbE)        : r0 = relu(x @ w_embed) -> bf16
//   blocks [nbE,nbE+nbI)  : both CSR indptrs by binary search
//   blocks [nbE+nbI,+nbT) : warm-touch A2 col+val into LLC
// ---------------------------------------------------------------------------
__global__ void prep_kernel(const float* __restrict__ x,
                            const float* __restrict__ w,
                            ushort* __restrict__ r0,
                            const int* __restrict__ a1r, int E1, int* __restrict__ ip1,
                            const int* __restrict__ a2r, int E2, int* __restrict__ ip2,
                            const int* __restrict__ a2c, const float* __restrict__ a2v,
                            float* __restrict__ dummy,
                            int n, int nbE, int nbI, int nbT) {
    __shared__ float wl[IN_C * HID];
    const int tid = threadIdx.x;
    if (blockIdx.x < nbE) {
        for (int i = tid; i < IN_C * HID; i += blockDim.x) wl[i] = w[i];
        __syncthreads();
        const int row = blockIdx.x * 16 + tid / 16;
        const int h0  = (tid % 16) * 2;
        if (row >= n) return;
        const float4* xr = (const float4*)(x + (size_t)row * IN_C);
        float a0 = 0.f, a1 = 0.f;
#pragma unroll
        for (int k4 = 0; k4 < IN_C / 4; ++k4) {
            float4 xv = xr[k4];
            a0 += xv.x * wl[(4*k4+0)*HID + h0];  a1 += xv.x * wl[(4*k4+0)*HID + h0+1];
            a0 += xv.y * wl[(4*k4+1)*HID + h0];  a1 += xv.y * wl[(4*k4+1)*HID + h0+1];
            a0 += xv.z * wl[(4*k4+2)*HID + h0];  a1 += xv.z * wl[(4*k4+2)*HID + h0+1];
            a0 += xv.w * wl[(4*k4+3)*HID + h0];  a1 += xv.w * wl[(4*k4+3)*HID + h0+1];
        }
        uint p = f2bf(fmaxf(a0, 0.f)) | (f2bf(fmaxf(a1, 0.f)) << 16);
        ((uint*)r0)[(size_t)row * 16 + (tid % 16)] = p;
    } else if (blockIdx.x < nbE + nbI) {
        const int i = (blockIdx.x - nbE) * 256 + tid;
        if (i > n) return;
        int lo = 0, hi = E1;
        while (lo < hi) { int m = (lo + hi) >> 1; if (a1r[m] < i) lo = m + 1; else hi = m; }
        ip1[i] = lo;
        lo = 0; hi = E2;
        while (lo < hi) { int m = (lo + hi) >> 1; if (a2r[m] < i) lo = m + 1; else hi = m; }
        ip2[i] = lo;
    } else {
        const int t = (blockIdx.x - nbE - nbI) * 256 + tid;
        const int stride = nbT * 256;
        const int total4 = E2 / 4;
        const float4* c4 = (const float4*)a2c;
        const float4* v4 = (const float4*)a2v;
        float s = 0.f;
        for (int i = t; i < total4; i += stride) {
            float4 u = c4[i], v = v4[i];
            s += u.x + u.y + u.z + u.w + v.x + v.y + v.z + v.w;
        }
        if (s == 123.456f) dummy[0] = s;   // defeats DCE; never taken in practice
    }
}

// ---------------------------------------------------------------------------
// K2: level-1 SpMM + ReLU (with val), bf16 / fp32 acc. R10 structure.
// ROWS=2 rows/wave; L=4 feature-lanes x W=8 ways, 4-edge int4 batches.
// Epilogue also emits y1/y2 = dis1/dis2-scaled outputs for level 2.
// Blocks [0,nb2) = A2 (out col off C); rest = A1 (off 0).
// ---------------------------------------------------------------------------
template <int C, int ROWS>
__global__ __launch_bounds__(256) void spmm_l1(
        const int* __restrict__ ip1, const int* __restrict__ col1,
        const float* __restrict__ val1,
        const int* __restrict__ ip2, const int* __restrict__ col2,
        const float* __restrict__ val2,
        const ushort* __restrict__ xin,
        ushort* __restrict__ rout,
        ushort* __restrict__ yout1, ushort* __restrict__ yout2,
        int n, int nb2) {
    constexpr int L    = C / 8;
    constexpr int SUBL = 64 / ROWS;
    constexpr int W    = SUBL / L;
    const int lane = threadIdx.x & 63;
    const int wave = threadIdx.x >> 6;
    const int sub  = lane / SUBL;
    const int li   = lane % SUBL;
    const int fl   = li % L;
    const int way  = li / L;

    int bid = blockIdx.x;
    const int* ip; const int* col; const float* val; int off;
    if (bid < nb2) {             ip = ip2; col = col2; val = val2; off = C; }
    else           { bid -= nb2; ip = ip1; col = col1; val = val1; off = 0; }

    const int row = (bid * 4 + wave) * ROWS + sub;
    if (row >= n) return;

    const ushort* xbase = xin + fl * 8;
    float acc[8];
#pragma unroll
    for (int j = 0; j < 8; ++j) acc[j] = 0.f;

    auto gat = [&](int c) -> uint4 { return *(const uint4*)(xbase + (size_t)c * C); };
    auto fmadd = [&](const uint4& u, float v) {
        acc[0] += v * bf_lo(u.x); acc[1] += v * bf_hi(u.x);
        acc[2] += v * bf_lo(u.y); acc[3] += v * bf_hi(u.y);
        acc[4] += v * bf_lo(u.z); acc[5] += v * bf_hi(u.z);
        acc[6] += v * bf_lo(u.w); acc[7] += v * bf_hi(u.w);
    };

    const int s = ip[row];
    const int e = ip[row + 1];
    int sv = (s + 3) & ~3; if (sv > e) sv = e;
    const int nv = (e - sv) / (4 * W);

    for (int idx = s + way; idx < sv; idx += W) fmadd(gat(col[idx]), val[idx]);
    const int*   cb = col + sv;
    const float* vb = val + sv;
    for (int i = 0; i < nv; ++i) {
        const int base = (i * W + way) * 4;
        const int4   cc = *(const int4*)  (cb + base);
        const float4 vv = *(const float4*)(vb + base);
        const uint4 g0 = gat(cc.x), g1 = gat(cc.y), g2 = gat(cc.z), g3 = gat(cc.w);
        fmadd(g0, vv.x); fmadd(g1, vv.y); fmadd(g2, vv.z); fmadd(g3, vv.w);
    }
    for (int idx = sv + nv * 4 * W + way; idx < e; idx += W)
        fmadd(gat(col[idx]), val[idx]);

#pragma unroll
    for (int m = L; m < SUBL; m <<= 1)
#pragma unroll
        for (int j = 0; j < 8; ++j) acc[j] += __shfl_xor(acc[j], m, 64);

    if (way == 0) {
        float r[8];
#pragma unroll
        for (int j = 0; j < 8; ++j) r[j] = fmaxf(acc[j], 0.f);

        const size_t oidx = (size_t)row * (2 * C) + off + fl * 8;
        uint4 p;
        p.x = f2bf(r[0]) | (f2bf(r[1]) << 16);
        p.y = f2bf(r[2]) | (f2bf(r[3]) << 16);
        p.z = f2bf(r[4]) | (f2bf(r[5]) << 16);
        p.w = f2bf(r[6]) | (f2bf(r[7]) << 16);
        *(uint4*)(rout + oidx) = p;

        const float s1 = inv_sqrt_deg(ip1[row + 1] - ip1[row]);
        const float s2 = inv_sqrt_deg(ip2[row + 1] - ip2[row]);
        uint4 q1, q2;
        q1.x = f2bf(s1*r[0]) | (f2bf(s1*r[1]) << 16);
        q1.y = f2bf(s1*r[2]) | (f2bf(s1*r[3]) << 16);
        q1.z = f2bf(s1*r[4]) | (f2bf(s1*r[5]) << 16);
        q1.w = f2bf(s1*r[6]) | (f2bf(s1*r[7]) << 16);
        q2.x = f2bf(s2*r[0]) | (f2bf(s2*r[1]) << 16);
        q2.y = f2bf(s2*r[2]) | (f2bf(s2*r[3]) << 16);
        q2.z = f2bf(s2*r[4]) | (f2bf(s2*r[5]) << 16);
        q2.w = f2bf(s2*r[6]) | (f2bf(s2*r[7]) << 16);
        *(uint4*)(yout1 + oidx) = q1;
        *(uint4*)(yout2 + oidx) = q2;
    }
}

// ---------------------------------------------------------------------------
// K3: FUSED level-2 SpMM + ReLU + classify, bank-conflict-free classify.
// One wave per row. Gather phase as R12 (val-free, L=8 x W=8). Then the full
// concat row (224 floats) is staged into a PER-WAVE LDS buffer (r2 from
// registers, r1/r0 via coalesced uint4 loads), and classify runs with
// lane = (op-pair lane&7) x (feature-eighth lane>>3):
//   rrow reads: 8 distinct addrs, 16-lane broadcast each -> conflict-free
//   wl stored [f][o] pad-18: addr = 24*(qt%4)+18*jj+op (mod 32) -> <=2/bank
// float2 weight reads; 3-stage shfl reduce over qt; 8 float2 stores per row.
// ---------------------------------------------------------------------------
__global__ __launch_bounds__(256) void spmm2_cls(
        const int* __restrict__ ip1, const int* __restrict__ col1,
        const int* __restrict__ ip2, const int* __restrict__ col2,
        const ushort* __restrict__ y1, const ushort* __restrict__ y2,
        const ushort* __restrict__ r0, const ushort* __restrict__ r1,
        const float* __restrict__ w, float* __restrict__ out, int n) {
    __shared__ float wl[CDIM * 18];        // [f][o], stride 18 (pad)
    __shared__ float rrow[4][CDIM];        // per-wave concat row
    for (int i = threadIdx.x; i < CDIM * OUT_C; i += 256)
        wl[(i >> 4) * 18 + (i & 15)] = w[i];
    // barrier deferred: wl/rrow first read after the gather phase

    const int lane = threadIdx.x & 63;
    const int wave = threadIdx.x >> 6;
    const int row  = blockIdx.x * 4 + wave;
    const int fl   = lane & 7;     // feature chunk (8 bf16 = uint4)
    const int way  = lane >> 3;    // edge way

    float acc1[8], acc2[8];
#pragma unroll
    for (int j = 0; j < 8; ++j) { acc1[j] = 0.f; acc2[j] = 0.f; }
    int deg1 = 0, deg2 = 0;

    if (row < n) {
        auto half = [&](const int* __restrict__ ip, const int* __restrict__ col,
                        const ushort* __restrict__ yb, float* acc, int& deg) {
            const int s = ip[row];
            const int e = ip[row + 1];
            deg = e - s;
            const ushort* xbase = yb + fl * 8;
            auto gat = [&](int c) -> uint4 {
                return *(const uint4*)(xbase + (size_t)c * 64);
            };
            auto aadd = [&](const uint4& u) {
                acc[0] += bf_lo(u.x); acc[1] += bf_hi(u.x);
                acc[2] += bf_lo(u.y); acc[3] += bf_hi(u.y);
                acc[4] += bf_lo(u.z); acc[5] += bf_hi(u.z);
                acc[6] += bf_lo(u.w); acc[7] += bf_hi(u.w);
            };
            int sv = (s + 3) & ~3; if (sv > e) sv = e;
            const int nv = (e - sv) / 32;          // 4 edges x 8 ways
            for (int idx = s + way; idx < sv; idx += 8) aadd(gat(col[idx]));
            const int* cb = col + sv;
            for (int i = 0; i < nv; ++i) {
                const int base = (i * 8 + way) * 4;
                const int4 cc = *(const int4*)(cb + base);
                const uint4 g0 = gat(cc.x), g1 = gat(cc.y),
                            g2 = gat(cc.z), g3 = gat(cc.w);
                aadd(g0); aadd(g1); aadd(g2); aadd(g3);
            }
            for (int idx = sv + nv * 32 + way; idx < e; idx += 8) aadd(gat(col[idx]));
        };
        half(ip2, col2, y2, acc2, deg2);   // heavy half first
        half(ip1, col1, y1, acc1, deg1);

        // reduce to way==0 lanes (butterfly keeps it simple)
#pragma unroll
        for (int m = 8; m < 64; m <<= 1)
#pragma unroll
            for (int j = 0; j < 8; ++j) {
                acc1[j] += __shfl_xor(acc1[j], m, 64);
                acc2[j] += __shfl_xor(acc2[j], m, 64);
            }

        // stage concat row into per-wave LDS
        if (way == 0) {
            const float s1v = inv_sqrt_deg(deg1);
            const float s2v = inv_sqrt_deg(deg2);
#pragma unroll
            for (int j = 0; j < 8; ++j) {
                rrow[wave][96  + fl * 8 + j] = fmaxf(s1v * acc1[j], 0.f);
                rrow[wave][160 + fl * 8 + j] = fmaxf(s2v * acc2[j], 0.f);
            }
        } else if (way == 1) {
            const uint4 u = ((const uint4*)(r1 + (size_t)row * 64))[fl];
            float* d = &rrow[wave][32 + fl * 8];
            d[0]=bf_lo(u.x); d[1]=bf_hi(u.x); d[2]=bf_lo(u.y); d[3]=bf_hi(u.y);
            d[4]=bf_lo(u.z); d[5]=bf_hi(u.z); d[6]=bf_lo(u.w); d[7]=bf_hi(u.w);
        } else if (way == 2 && fl < 4) {
            const uint4 u = ((const uint4*)(r0 + (size_t)row * 32))[fl];
            float* d = &rrow[wave][fl * 8];
            d[0]=bf_lo(u.x); d[1]=bf_hi(u.x); d[2]=bf_lo(u.y); d[3]=bf_hi(u.y);
            d[4]=bf_lo(u.z); d[5]=bf_hi(u.z); d[6]=bf_lo(u.w); d[7]=bf_hi(u.w);
        }
    }

    __syncthreads();                       // wl + rrow ready
    if (row >= n) return;

    // classify: lane = (op-pair lane&7) x (feature-eighth lane>>3)
    const int op = (lane & 7) * 2;         // output pair {op, op+1}
    const int qt = lane >> 3;              // 28 features per eighth
    float q0 = 0.f, q1 = 0.f;
    const float* rr = &rrow[wave][qt * 28];
    const float* wb = &wl[(qt * 28) * 18 + op];
#pragma unroll
    for (int jj = 0; jj < 28; ++jj) {
        const float  rv = rr[jj];
        const float2 wv = *(const float2*)(wb + jj * 18);
        q0 += rv * wv.x;  q1 += rv * wv.y;
    }
#pragma unroll
    for (int m = 8; m < 64; m <<= 1) {
        q0 += __shfl_xor(q0, m, 64);
        q1 += __shfl_xor(q1, m, 64);
    }
    if (qt == 0) {
        float2 v; v.x = q0; v.y = q1;
        *(float2*)(out + (size_t)row * OUT_C + op) = v;
    }
}

// ---------------------------------------------------------------------------
extern "C" void kernel_launch(void* const* d_in, const int* in_sizes, int n_in,
                              void* d_out, int out_size, void* d_ws, size_t ws_size,
                              hipStream_t stream) {
    const float* x   = (const float*)d_in[0];
    const float* we  = (const float*)d_in[1];
    const float* wc  = (const float*)d_in[2];
    const int*   a1r = (const int*)  d_in[3];
    const int*   a1c = (const int*)  d_in[4];
    const float* a1v = (const float*)d_in[5];
    const int*   a2r = (const int*)  d_in[6];
    const int*   a2c = (const int*)  d_in[7];
    const float* a2v = (const float*)d_in[8];
    float* out = (float*)d_out;

    const int E1 = in_sizes[3];
    const int E2 = in_sizes[6];
    const int n  = in_sizes[0] / IN_C;   // 20000

    // Workspace (bf16): r0[n*32] r1[n*64] y1_1[n*64] y2_1[n*64],
    // then ip1/ip2/dummy (int)
    ushort* r0   = (ushort*)d_ws;
    ushort* r1   = r0   + (size_t)n * 32;
    ushort* y1_1 = r1   + (size_t)n * 64;
    ushort* y2_1 = y1_1 + (size_t)n * 64;
    int*    ip1  = (int*)(y2_1 + (size_t)n * 64);
    int*    ip2  = ip1 + (n + 1);
    float*  dummy = (float*)(ip2 + (n + 1));

    // K1: fused prep (embed + indptrs + warm-touch)
    {
        const int nbE = (n + 15) / 16;
        const int nbI = (n + 1 + 255) / 256;
        const int nbT = 512;
        prep_kernel<<<nbE + nbI + nbT, 256, 0, stream>>>(
            x, we, r0, a1r, E1, ip1, a2r, E2, ip2, a2c, a2v, dummy,
            n, nbE, nbI, nbT);
    }
    // K2: level 1 (C=32, ROWS=2, with val) + scaled outputs for level 2
    {
        const int nb = (n + 7) / 8;
        spmm_l1<32, 2><<<2 * nb, 256, 0, stream>>>(
            ip1, a1c, a1v, ip2, a2c, a2v, r0, r1, y1_1, y2_1, n, nb);
    }
    // K3: fused level 2 + classify (one wave per row)
    {
        const int nb = (n + 3) / 4;
        spmm2_cls<<<nb, 256, 0, stream>>>(
            ip1, a1c, ip2, a2c, y1_1, y2_1, r0, r1, wc, out, n);
    }
}